// Round 10
// baseline (481.703 us; speedup 1.0000x reference)
//
#include <hip/hip_runtime.h>
#include <hip/hip_fp16.h>

#define NUSR 100000
#define NITM 50000
#define NEDG 1000000
#define NPRED 250000
#define DD 64
#define DD2 128
#define MSG_EPS 1e-7f
#define BN_EPS 1e-5f
#define LOG2E 1.44269504088896340736f
#define LN2F 0.69314718055994530942f

// CSR-build bucketing: items W=512 (shift 9), users W=1024 (shift 10) -> 98 buckets each.
#define KI 98
#define KU 98
#define BCAP 16384  // per-bucket pair capacity (mean 10240, sd ~100 -> 40+ sigma)
#define EPB 4096    // edges per part_k block
#define ICAP 1536   // LDS-staged csr entries per aggemm1 block (overflow -> global path)

typedef _Float16 f16x8 __attribute__((ext_vector_type(8)));
typedef float f32x4 __attribute__((ext_vector_type(4)));

// Journal: R18 deleted count_k (80us atomic-writeback pathology) -> 475us.
// Gather stuck 86-90us across R12..R17 variants (arith/ILP/occupancy all
// falsified). R19 theory: WITHIN-WAVE degree divergence — 8 row-groups/wave in
// lockstep cost max(deg_1..8) per pull (Poisson: +45% items, +70% users).
// Fix: degree-sorted pull order (order[] ranked by deg; concurrent pulls get
// near-equal degrees -> max~mean). Numerics bit-identical.

__device__ __forceinline__ float exp2a(float x) {
    float r; asm("v_exp_f32 %0, %1" : "=v"(r) : "v"(x)); return r;
}

// ---- phase 1: partition edges into fixed-capacity bucket pair slots ------------
// Pair packing (27 bits): items (dstoff<<17)|src_user; users (dstoff<<16)|src_item.
__global__ __launch_bounds__(256) void part_k(
    const int* __restrict__ u_idx, const int* __restrict__ i_idx,
    int* __restrict__ bkcnt_i, int* __restrict__ bkcnt_u,
    int* __restrict__ pair_i, int* __restrict__ pair_u)
{
    __shared__ int lh_i[KI], lh_u[KU];
    __shared__ int lb_i[KI], lb_u[KU];
    int tid = threadIdx.x;
    int base = blockIdx.x * EPB;
    int u[16], it[16];
    #pragma unroll
    for (int q = 0; q < 16; q++) {
        int e = base + q * 256 + tid;
        u[q]  = (e < NEDG) ? u_idx[e] : -1;
        it[q] = (e < NEDG) ? i_idx[e] : -1;
    }
    if (tid < KI) lh_i[tid] = 0;
    if (tid >= 128 && tid < 128 + KU) lh_u[tid - 128] = 0;
    __syncthreads();
    #pragma unroll
    for (int q = 0; q < 16; q++) if (it[q] >= 0) {
        atomicAdd(&lh_i[it[q] >> 9], 1);
        atomicAdd(&lh_u[u[q] >> 10], 1);
    }
    __syncthreads();
    if (tid < KI) {
        int c = lh_i[tid];
        lb_i[tid] = tid * BCAP + (c ? atomicAdd(&bkcnt_i[tid], c) : 0);
    }
    if (tid >= 128 && tid < 128 + KU) {
        int k = tid - 128; int c = lh_u[k];
        lb_u[k] = k * BCAP + (c ? atomicAdd(&bkcnt_u[k], c) : 0);
    }
    __syncthreads();
    #pragma unroll
    for (int q = 0; q < 16; q++) if (it[q] >= 0) {
        int pi_ = atomicAdd(&lb_i[it[q] >> 9], 1);
        pair_i[pi_] = ((it[q] & 511) << 17) | u[q];
        int pu_ = atomicAdd(&lb_u[u[q] >> 10], 1);
        pair_u[pu_] = ((u[q] & 1023) << 16) | it[q];
    }
}

// ---- exclusive scan of 98 bucket counts per side (2 blocks x 128) --------------
__global__ __launch_bounds__(128) void bsum2_k(
    const int* __restrict__ bkcnt_i, const int* __restrict__ bkcnt_u,
    int* __restrict__ bbase_i, int* __restrict__ bbase_u)
{
    __shared__ int s[128];
    const int* cnt = (blockIdx.x == 0) ? bkcnt_i : bkcnt_u;
    int* bas = (blockIdx.x == 0) ? bbase_i : bbase_u;
    int t = threadIdx.x;
    int v = (t < KI) ? cnt[t] : 0;
    s[t] = v;
    __syncthreads();
    for (int off = 1; off < 128; off <<= 1) {
        int tv = (t >= off) ? s[t - off] : 0;
        __syncthreads();
        s[t] += tv;
        __syncthreads();
    }
    if (t < KI) bas[t] = s[t] - v;
}

// ---- phase 2: per-bucket block: LDS hist -> LDS scan -> rowptr (coalesced) ->
// LDS-cursor scatter. NO global degree/cursor atomics anywhere. Idempotent.
__global__ __launch_bounds__(1024) void bscat2_k(
    const int* __restrict__ pair_i, const int* __restrict__ pair_u,
    const int* __restrict__ bkcnt_i, const int* __restrict__ bkcnt_u,
    const int* __restrict__ bbase_i, const int* __restrict__ bbase_u,
    int* __restrict__ rowptr_i, int* __restrict__ rowptr_u,
    int* __restrict__ csr_i, int* __restrict__ csr_u)
{
    __shared__ int s[1024];
    __shared__ int cur[1024];
    int b = blockIdx.x;
    const int* pair; int* rowptr; int* csr;
    int base_row, wrows, n, shsrc, cnt, base;
    if (b < KI) {
        pair = pair_i + (size_t)b * BCAP; cnt = bkcnt_i[b]; base = bbase_i[b];
        rowptr = rowptr_i; csr = csr_i; base_row = b << 9; wrows = 512; n = NITM; shsrc = 17;
    } else {
        int k = b - KI;
        pair = pair_u + (size_t)k * BCAP; cnt = bkcnt_u[k]; base = bbase_u[k];
        rowptr = rowptr_u; csr = csr_u; base_row = k << 10; wrows = 1024; n = NUSR; shsrc = 16;
    }
    int nrows = min(wrows, n - base_row);
    int t = threadIdx.x;
    s[t] = 0;
    __syncthreads();
    for (int e = t; e < cnt; e += 1024) atomicAdd(&s[pair[e] >> shsrc], 1);
    __syncthreads();
    int deg = s[t];
    for (int off = 1; off < 1024; off <<= 1) {
        int tv = (t >= off) ? s[t - off] : 0;
        __syncthreads();
        s[t] += tv;
        __syncthreads();
    }
    int rp = base + s[t] - deg;
    if (t < nrows) rowptr[base_row + t] = rp;
    cur[t] = rp;
    if (b == KI - 1 && t == 0) rowptr_i[NITM] = NEDG;
    if (b == KI + KU - 1 && t == 0) rowptr_u[NUSR] = NEDG;
    __syncthreads();
    int srcmask = (1 << shsrc) - 1;
    for (int e = t; e < cnt; e += 1024) {
        int v = pair[e];
        int pos = atomicAdd(&cur[v >> shsrc], 1);
        csr[pos] = v & srcmask;
    }
}

// ========== layer-0 tables: ef = fp16(m*log2e) [128B/row], xh = fp16(x) =========
__global__ __launch_bounds__(256) void msg0_k(
    const float* __restrict__ xu, const float* __restrict__ xi,
    __half* __restrict__ ef_u, __half* __restrict__ ef_i,
    __half* __restrict__ xh_u, __half* __restrict__ xh_i)
{
    int i = blockIdx.x * 256 + threadIdx.x;
    const float* x; __half* ef; __half* xh; int idx;
    if (i < NUSR * 16) { x = xu; ef = ef_u; xh = xh_u; idx = i; }
    else { int j = i - NUSR * 16; if (j >= NITM * 16) return; x = xi; ef = ef_i; xh = xh_i; idx = j; }
    float4 v = ((const float4*)x)[idx];
    float m0 = (fmaxf(v.x, 0.f) + MSG_EPS) * LOG2E;
    float m1 = (fmaxf(v.y, 0.f) + MSG_EPS) * LOG2E;
    float m2 = (fmaxf(v.z, 0.f) + MSG_EPS) * LOG2E;
    float m3 = (fmaxf(v.w, 0.f) + MSG_EPS) * LOG2E;
    __half2 e01 = __floats2half2_rn(m0, m1), e23 = __floats2half2_rn(m2, m3);
    __half2 x01 = __floats2half2_rn(v.x, v.y), x23 = __floats2half2_rn(v.z, v.w);
    uint2 ew, xw;
    ew.x = *(unsigned int*)&e01; ew.y = *(unsigned int*)&e23;
    xw.x = *(unsigned int*)&x01; xw.y = *(unsigned int*)&x23;
    ((uint2*)ef)[idx] = ew;
    ((uint2*)xh)[idx] = xw;
}

// ========== weight convert+transpose to fp16 (once per call) =====================
__global__ __launch_bounds__(256) void wconv_k(
    const float* __restrict__ W1, const float* __restrict__ W2,
    __half* __restrict__ W1t, __half* __restrict__ W2t)
{
    int idx = blockIdx.x * 256 + threadIdx.x;
    if (idx >= 6 * 8192) return;
    int m = idx >> 13, rem = idx & 8191;
    {   // W1 [64][128] -> [128][64]
        int k = rem >> 7, c = rem & 127;
        W1t[m * 8192 + c * 64 + k] = __float2half(W1[idx]);
    }
    {   // W2 [128][64] -> [64][128]
        int k = rem >> 6, c = rem & 63;
        W2t[m * 8192 + c * 128 + k] = __float2half(W2[idx]);
    }
}

// ===== FUSED (item-conv + user-conv) agg + GEMM1 (MFMA fp16) =====================
// den = sum 2^m', num' = sum 2^m' * m', agg = ln2 * num'/den.
// R19: degree-sorted dynamic pull (concurrent pulls get near-equal degrees ->
// per-pull cost max(deg)~mean(deg), killing within-wave lockstep divergence).
#define UPD4(U) { \
    float2 va=__half22float2(*(__half2*)&(U).x); \
    float2 vb=__half22float2(*(__half2*)&(U).y); \
    float2 vc=__half22float2(*(__half2*)&(U).z); \
    float2 vd=__half22float2(*(__half2*)&(U).w); \
    float e0=exp2a(va.x), e1=exp2a(va.y), e2=exp2a(vb.x), e3=exp2a(vb.y); \
    float e4=exp2a(vc.x), e5=exp2a(vc.y), e6=exp2a(vd.x), e7=exp2a(vd.y); \
    d0+=e0; n0=fmaf(e0,va.x,n0); d1+=e1; n1=fmaf(e1,va.y,n1); \
    d2+=e2; n2=fmaf(e2,vb.x,n2); d3+=e3; n3=fmaf(e3,vb.y,n3); \
    d4+=e4; n4=fmaf(e4,vc.x,n4); d5+=e5; n5=fmaf(e5,vc.y,n5); \
    d6+=e6; n6=fmaf(e6,vd.x,n6); d7+=e7; n7=fmaf(e7,vd.y,n7); }

#define GBODY(IDXE) { \
    int j = beg; \
    for (; j + 8 <= end; j += 8) { \
        int s0=(IDXE(j)),   s1=(IDXE(j+1)), s2=(IDXE(j+2)), s3=(IDXE(j+3)); \
        int s4=(IDXE(j+4)), s5=(IDXE(j+5)), s6=(IDXE(j+6)), s7=(IDXE(j+7)); \
        uint4 u0 = mp4[(size_t)s0*8+l8]; uint4 u1 = mp4[(size_t)s1*8+l8]; \
        uint4 u2 = mp4[(size_t)s2*8+l8]; uint4 u3 = mp4[(size_t)s3*8+l8]; \
        uint4 u4 = mp4[(size_t)s4*8+l8]; uint4 u5 = mp4[(size_t)s5*8+l8]; \
        uint4 u6 = mp4[(size_t)s6*8+l8]; uint4 u7 = mp4[(size_t)s7*8+l8]; \
        UPD4(u0) UPD4(u1) UPD4(u2) UPD4(u3) UPD4(u4) UPD4(u5) UPD4(u6) UPD4(u7) } \
    for (; j + 2 <= end; j += 2) { \
        int s0=(IDXE(j)), s1=(IDXE(j+1)); \
        uint4 u0 = mp4[(size_t)s0*8+l8]; uint4 u1 = mp4[(size_t)s1*8+l8]; \
        UPD4(u0) UPD4(u1) } \
    if (j < end) { int ss=(IDXE(j)); uint4 uu = mp4[(size_t)ss*8+l8]; UPD4(uu) } }

#define IDX_L(jj) su.idx[(jj)]
#define IDX_G(jj) csr[blkBeg + (jj)]

union AggSU { int idx[ICAP]; float red[8][128]; };

__global__ __launch_bounds__(256) void aggemm1f_k(
    const __half* __restrict__ ef_i_src, const __half* __restrict__ ef_u_src,
    const __half* __restrict__ xhi_cur, const __half* __restrict__ xhu_cur,
    const int* __restrict__ rowptr_i, const int* __restrict__ rowptr_u,
    const int* __restrict__ csr_i, const int* __restrict__ csr_u,
    const __half* __restrict__ W1t_l,   // layer base: [2][128][64] f16
    const float* __restrict__ b1_l,     // [2][128]
    __half* __restrict__ h1_i, __half* __restrict__ h1_u,   // fp16 h1
    double* __restrict__ gs_l,          // [2][256] (gsum|gsq per conv)
    int gI)
{
    __shared__ _Float16 sA[64][88];      // 11.3 KB, rows 16B-aligned
    __shared__ AggSU su;                 // 6 KB (idx) / 4 KB (red)
    __shared__ int srp[65];              // rowptr slice (relative to blkBeg)
    __shared__ int order[64];            // rows sorted by degree (desc)
    __shared__ int wq;                   // dynamic row queue

    int side = ((int)blockIdx.x < gI) ? 0 : 1;
    int bb = side ? (blockIdx.x - gI) : blockIdx.x;
    const __half* ef  = side ? ef_i_src : ef_u_src;   // side0 (item dst) gathers USER msgs
    const __half* xh  = side ? xhu_cur : xhi_cur;     // dst features
    const int* rowptr = side ? rowptr_u : rowptr_i;
    const int* csr    = side ? csr_u : csr_i;
    const __half* W1t = W1t_l + (size_t)side * 8192;
    const float* b1   = b1_l + side * DD2;
    __half* h1        = side ? h1_u : h1_i;
    double* gsum      = gs_l + side * 256;
    double* gsq       = gsum + 128;
    int N             = side ? NUSR : NITM;

    int t = threadIdx.x;
    int r0 = bb * 64;
    int w = t >> 6, lane = t & 63;
    int g = lane >> 3, l8 = lane & 7;          // gather layout: 8 lanes/row
    int q = lane >> 4, ln = lane & 15;         // MFMA layout
    const uint4* mp4 = (const uint4*)ef;

    // ---- stage csr slice + rowptr slice (coalesced, off the dependent chain) --
    int blkBeg = rowptr[r0];
    if (t == 0) wq = 0;
    if (t < 65) srp[t] = rowptr[min(r0 + t, N)] - blkBeg;
    int blkEnd = rowptr[min(r0 + 64, N)];
    int nE = blkEnd - blkBeg;
    for (int e = t; e < nE && e < ICAP; e += 256) su.idx[e] = csr[blkBeg + e];
    __syncthreads();

    // ---- degree-rank the 64 rows (desc); ties by index. O(64) per thread. ----
    if (t < 64) {
        int myd = srp[t + 1] - srp[t];
        int rank = 0;
        #pragma unroll
        for (int j = 0; j < 64; j++) {
            int dj = srp[j + 1] - srp[j];
            rank += (dj > myd) || (dj == myd && j < t);
        }
        order[rank] = t;
    }
    __syncthreads();

    // ---- gather + softmax-agg: 32 groups pull degree-sorted rows --------------
    for (;;) {
        int k = 0;
        if (l8 == 0) k = atomicAdd(&wq, 1);
        k = __shfl(k, g * 8);
        if (k >= 64) break;
        int rr = order[k];
        int r = r0 + rr;
        uint4 o = make_uint4(0u, 0u, 0u, 0u);
        if (r < N) {
            uint4 xv = ((const uint4*)xh)[(size_t)r * 8 + l8];   // early, independent
            int beg = srp[rr], end = srp[rr + 1];
            float d0=0.f,d1=0.f,d2=0.f,d3=0.f,d4=0.f,d5=0.f,d6=0.f,d7=0.f;
            float n0=0.f,n1=0.f,n2=0.f,n3=0.f,n4=0.f,n5=0.f,n6=0.f,n7=0.f;
            if (end <= ICAP) { GBODY(IDX_L) } else { GBODY(IDX_G) }
            bool nz = end > beg;
            float a0 = nz ? (n0/d0)*LN2F : 0.f, a1 = nz ? (n1/d1)*LN2F : 0.f;
            float a2 = nz ? (n2/d2)*LN2F : 0.f, a3 = nz ? (n3/d3)*LN2F : 0.f;
            float a4 = nz ? (n4/d4)*LN2F : 0.f, a5 = nz ? (n5/d5)*LN2F : 0.f;
            float a6 = nz ? (n6/d6)*LN2F : 0.f, a7 = nz ? (n7/d7)*LN2F : 0.f;
            float2 x01 = __half22float2(*(__half2*)&xv.x);
            float2 x23 = __half22float2(*(__half2*)&xv.y);
            float2 x45 = __half22float2(*(__half2*)&xv.z);
            float2 x67 = __half22float2(*(__half2*)&xv.w);
            __half2 p0 = __floats2half2_rn(a0 + x01.x, a1 + x01.y);
            __half2 p1 = __floats2half2_rn(a2 + x23.x, a3 + x23.y);
            __half2 p2 = __floats2half2_rn(a4 + x45.x, a5 + x45.y);
            __half2 p3 = __floats2half2_rn(a6 + x67.x, a7 + x67.y);
            o.x = *(unsigned int*)&p0; o.y = *(unsigned int*)&p1;
            o.z = *(unsigned int*)&p2; o.w = *(unsigned int*)&p3;
        }
        *(uint4*)&sA[rr][l8 * 8] = o;
    }
    __syncthreads();

    f16x8 afr[4][2], bfr[2][2];
    #pragma unroll
    for (int rt = 0; rt < 4; rt++)
        #pragma unroll
        for (int ks = 0; ks < 2; ks++)
            afr[rt][ks] = *(const f16x8*)&sA[rt * 16 + ln][ks * 32 + q * 8];
    const f16x8* Wv = (const f16x8*)W1t;   // [row 0..127][k-frag]: idx = row*8 + ks*4 + q
    #pragma unroll
    for (int ct = 0; ct < 2; ct++)
        #pragma unroll
        for (int ks = 0; ks < 2; ks++)
            bfr[ct][ks] = Wv[(w * 32 + ct * 16 + ln) * 8 + ks * 4 + q];

    f32x4 acc[4][2];
    #pragma unroll
    for (int rt = 0; rt < 4; rt++)
        #pragma unroll
        for (int ct = 0; ct < 2; ct++)
            acc[rt][ct] = (f32x4){0.f, 0.f, 0.f, 0.f};

    #pragma unroll
    for (int rt = 0; rt < 4; rt++)
        #pragma unroll
        for (int ct = 0; ct < 2; ct++) {
            acc[rt][ct] = __builtin_amdgcn_mfma_f32_16x16x32_f16(
                afr[rt][0], bfr[ct][0], acc[rt][ct], 0, 0, 0);
            acc[rt][ct] = __builtin_amdgcn_mfma_f32_16x16x32_f16(
                afr[rt][1], bfr[ct][1], acc[rt][ct], 0, 0, 0);
        }

    float b1c0 = b1[w * 32 + ln];
    float b1c1 = b1[w * 32 + 16 + ln];
    float ps0 = 0.f, pq0 = 0.f, ps1 = 0.f, pq1 = 0.f;
    #pragma unroll
    for (int rt = 0; rt < 4; rt++) {
        #pragma unroll
        for (int i = 0; i < 4; i++) {
            int r = r0 + rt * 16 + q * 4 + i;
            if (r < N) {
                float h0 = acc[rt][0][i] + b1c0;
                float h1v = acc[rt][1][i] + b1c1;
                h1[(size_t)r * DD2 + w * 32 + ln] = __float2half(h0);
                h1[(size_t)r * DD2 + w * 32 + 16 + ln] = __float2half(h1v);
                ps0 += h0; pq0 += h0 * h0;
                ps1 += h1v; pq1 += h1v * h1v;
            }
        }
    }
    // su.idx is dead (last read before the pre-MFMA barrier) -> reuse as red scratch
    su.red[q][w * 32 + ln] = ps0;      su.red[q][w * 32 + 16 + ln] = ps1;
    su.red[4 + q][w * 32 + ln] = pq0;  su.red[4 + q][w * 32 + 16 + ln] = pq1;
    __syncthreads();
    if (t < 128) {
        float s = 0.f, qq = 0.f;
        #pragma unroll
        for (int k = 0; k < 4; k++) { s += su.red[k][t]; qq += su.red[4 + k][t]; }
        atomicAdd(&gsum[t], (double)s);
        atomicAdd(&gsq[t],  (double)qq);
    }
}

// ===== FUSED GEMM2 (both convs): xnew = relu(relu(bn(h1)) @ W2 + b2) ============
// last=0: write fp16 xh + fp16 ef (m*log2e). last=1: write f32 xnew only.
__global__ __launch_bounds__(256) void gemm2f_k(
    const __half* __restrict__ h1_i, const __half* __restrict__ h1_u,
    const double* __restrict__ gs_l,
    const float* __restrict__ gamma_l, const float* __restrict__ beta_l,
    const __half* __restrict__ W2t_l, const float* __restrict__ b2_l,
    float* __restrict__ xi_new, float* __restrict__ xu_new,
    __half* __restrict__ xhi_out, __half* __restrict__ xhu_out,
    __half* __restrict__ efi_out, __half* __restrict__ efu_out,
    int last, int gI)
{
    __shared__ _Float16 sA[64][136];    // 17.4 KB
    __shared__ float2 sss[DD2];         // 1 KB

    int side = ((int)blockIdx.x < gI) ? 0 : 1;
    int bb = side ? (blockIdx.x - gI) : blockIdx.x;
    const __half* h1   = side ? h1_u : h1_i;
    const double* gsum = gs_l + side * 256;
    const double* gsq  = gsum + 128;
    const float* gamma = gamma_l + side * DD2;
    const float* beta  = beta_l + side * DD2;
    const __half* W2t  = W2t_l + (size_t)side * 8192;
    const float* b2    = b2_l + side * DD;
    float* xnew        = side ? xu_new : xi_new;
    __half* xhout      = side ? xhu_out : xhi_out;
    __half* efout      = side ? efu_out : efi_out;
    int N              = side ? NUSR : NITM;

    int t = threadIdx.x;
    if (t < 128) {
        double mean = gsum[t] / (double)N;
        double var  = gsq[t] / (double)N - mean * mean;
        float inv = (float)(1.0 / sqrt(var + (double)BN_EPS));
        float sc = gamma[t] * inv;
        sss[t] = make_float2(sc, beta[t] - (float)mean * sc);
    }
    __syncthreads();

    int r0 = bb * 64;
    // stage h1 (fp16) with BN + relu -> fp16: 64 rows x 32 uint2 (4 halves each)
    for (int i = t; i < 2048; i += 256) {
        int rr = i >> 5, c4 = i & 31;
        int r = r0 + rr;
        uint2 o = make_uint2(0u, 0u);
        if (r < N) {
            uint2 hv = ((const uint2*)h1)[(size_t)r * 32 + c4];
            float2 va = __half22float2(*(__half2*)&hv.x);
            float2 vb = __half22float2(*(__half2*)&hv.y);
            float2 s0 = sss[c4 * 4], s1 = sss[c4 * 4 + 1];
            float2 s2 = sss[c4 * 4 + 2], s3 = sss[c4 * 4 + 3];
            va.x = fmaxf(fmaf(va.x, s0.x, s0.y), 0.f);
            va.y = fmaxf(fmaf(va.y, s1.x, s1.y), 0.f);
            vb.x = fmaxf(fmaf(vb.x, s2.x, s2.y), 0.f);
            vb.y = fmaxf(fmaf(vb.y, s3.x, s3.y), 0.f);
            __half2 a = __floats2half2_rn(va.x, va.y);
            __half2 b = __floats2half2_rn(vb.x, vb.y);
            o.x = *(unsigned int*)&a; o.y = *(unsigned int*)&b;
        }
        *(uint2*)&sA[rr][c4 * 4] = o;
    }
    __syncthreads();

    int w = t >> 6, lane = t & 63, q = lane >> 4, ln = lane & 15;
    f32x4 acc[4];
    #pragma unroll
    for (int rt = 0; rt < 4; rt++) acc[rt] = (f32x4){0.f, 0.f, 0.f, 0.f};

    const f16x8* Wv = (const f16x8*)W2t;   // [row 0..63][k-frag]: idx = row*16 + ks*4 + q
    #pragma unroll
    for (int ks = 0; ks < 4; ks++) {
        f16x8 bf = Wv[(w * 16 + ln) * 16 + ks * 4 + q];
        #pragma unroll
        for (int rt = 0; rt < 4; rt++) {
            f16x8 af = *(const f16x8*)&sA[rt * 16 + ln][ks * 32 + q * 8];
            acc[rt] = __builtin_amdgcn_mfma_f32_16x16x32_f16(af, bf, acc[rt], 0, 0, 0);
        }
    }

    int c = w * 16 + ln;
    float bb2 = b2[c];
    #pragma unroll
    for (int rt = 0; rt < 4; rt++) {
        #pragma unroll
        for (int i = 0; i < 4; i++) {
            int r = r0 + rt * 16 + q * 4 + i;
            if (r < N) {
                float o = fmaxf(acc[rt][i] + bb2, 0.f);
                if (last) {
                    xnew[(size_t)r * DD + c] = o;
                } else {
                    xhout[(size_t)r * DD + c] = __float2half(o);
                    efout[(size_t)r * DD + c] = __float2half((o + MSG_EPS) * LOG2E);
                }
            }
        }
    }
}

// ================= decoder ========================================================
__global__ __launch_bounds__(256) void decode_k(
    const float* __restrict__ xu, const float* __restrict__ xi,
    const int* __restrict__ pu, const int* __restrict__ pi,
    float* __restrict__ out)
{
    int idx = blockIdx.x * 256 + threadIdx.x;
    int b = idx >> 4, lane = idx & 15;
    if (b >= NPRED) return;
    int u = pu[b], it = pi[b];
    float4 a = ((const float4*)(xu + (size_t)u * DD))[lane];
    float4 c = ((const float4*)(xi + (size_t)it * DD))[lane];
    float s = a.x * c.x + a.y * c.y + a.z * c.z + a.w * c.w;
    #pragma unroll
    for (int off = 8; off; off >>= 1) s += __shfl_down(s, off, 16);
    if (lane == 0) out[b] = s;
}

extern "C" void kernel_launch(void* const* d_in, const int* in_sizes, int n_in,
                              void* d_out, int out_size, void* d_ws, size_t ws_size,
                              hipStream_t stream)
{
    const float* x_user = (const float*)d_in[0];
    const float* x_item = (const float*)d_in[1];
    const float* W1    = (const float*)d_in[2];   // [3][2][64][128]
    const float* b1    = (const float*)d_in[3];
    const float* gamma = (const float*)d_in[4];
    const float* beta  = (const float*)d_in[5];
    const float* W2    = (const float*)d_in[6];   // [3][2][128][64]
    const float* b2    = (const float*)d_in[7];
    const int* edge = (const int*)d_in[8];        // [2][E]
    const int* pred = (const int*)d_in[9];        // [2][B]
    float* out = (float*)d_out;

    const int* u_idx = edge;
    const int* i_idx = edge + NEDG;

    // ---- workspace bump allocator (256B aligned chunks) ----
    char* p = (char*)d_ws;
    #define ALLOC(ptr, type, count) \
        type* ptr = (type*)p; p += (((size_t)(count) * sizeof(type)) + 255) & ~(size_t)255;

    ALLOC(gsumAll, double, 12 * 256)             // 6 convs x (gsum[128]|gsq[128])
    ALLOC(bkcnt_i, int, 128)
    ALLOC(bkcnt_u, int, 128)
    size_t zero_span = (char*)p - (char*)gsumAll;
    ALLOC(bbase_i, int, 128)
    ALLOC(bbase_u, int, 128)
    ALLOC(rowptr_i, int, NITM + 1)
    ALLOC(rowptr_u, int, NUSR + 1)
    ALLOC(csr_i, int, NEDG)
    ALLOC(csr_u, int, NEDG)
    ALLOC(h1_i, __half, (size_t)NITM * DD2)
    ALLOC(h1_u, __half, (size_t)NUSR * DD2)
    ALLOC(W1t, __half, 6 * 8192)
    ALLOC(W2t, __half, 6 * 8192)
    ALLOC(xu_f, float, (size_t)NUSR * DD)
    ALLOC(xi_f, float, (size_t)NITM * DD)
    ALLOC(xh_u0, __half, (size_t)NUSR * DD)
    ALLOC(xh_u1, __half, (size_t)NUSR * DD)
    ALLOC(xh_i0, __half, (size_t)NITM * DD)
    ALLOC(xh_i1, __half, (size_t)NITM * DD)
    ALLOC(ef_u, __half, (size_t)NUSR * DD)
    ALLOC(ef_i0, __half, (size_t)NITM * DD)
    ALLOC(ef_i1, __half, (size_t)NITM * DD)
    #undef ALLOC

    // fixed-capacity bucket pair slots alias h1 buffers: pairs are consumed by
    // bscat2_k strictly BEFORE aggemm1f_k first writes h1 (same stream).
    // pair_i 6.4MB <= h1_i 12.8MB; pair_u 6.4MB <= h1_u 25.6MB.
    int* pair_i = (int*)h1_i;
    int* pair_u = (int*)h1_u;

    // ---- CSR build + converts (once; reused by all 3 layers) ----
    hipMemsetAsync(gsumAll, 0, zero_span, stream);
    int pb = (NEDG + EPB - 1) / EPB;          // 245
    part_k<<<pb, 256, 0, stream>>>(u_idx, i_idx, bkcnt_i, bkcnt_u, pair_i, pair_u);
    bsum2_k<<<2, 128, 0, stream>>>(bkcnt_i, bkcnt_u, bbase_i, bbase_u);
    bscat2_k<<<KI + KU, 1024, 0, stream>>>(pair_i, pair_u, bkcnt_i, bkcnt_u,
                                           bbase_i, bbase_u, rowptr_i, rowptr_u,
                                           csr_i, csr_u);

    wconv_k<<<(6 * 8192 + 255) / 256, 256, 0, stream>>>(W1, W2, W1t, W2t);
    msg0_k<<<((NUSR + NITM) * 16 + 255) / 256, 256, 0, stream>>>(
        x_user, x_item, ef_u, ef_i0, xh_u0, xh_i0);

    // ---- 3 layers, each = 1 fused aggemm1 + 1 fused gemm2 ----
    int gI = (NITM + 63) / 64;    // 782 item blocks
    int gU = (NUSR + 63) / 64;    // 1563 user blocks
    __half* efi = ef_i0;
    __half* efi_alt = ef_i1;
    for (int l = 0; l < 3; l++) {
        const __half* xhi_c = (l & 1) ? xh_i1 : xh_i0;
        const __half* xhu_c = (l & 1) ? xh_u1 : xh_u0;
        __half* xhi_o = (l & 1) ? xh_i0 : xh_i1;
        __half* xhu_o = (l & 1) ? xh_u0 : xh_u1;
        aggemm1f_k<<<gI + gU, 256, 0, stream>>>(
            efi, ef_u, xhi_c, xhu_c, rowptr_i, rowptr_u, csr_i, csr_u,
            W1t + (size_t)l * 2 * 8192, b1 + (size_t)l * 2 * DD2,
            h1_i, h1_u, gsumAll + l * 2 * 256, gI);
        gemm2f_k<<<gI + gU, 256, 0, stream>>>(
            h1_i, h1_u, gsumAll + l * 2 * 256,
            gamma + (size_t)l * 2 * DD2, beta + (size_t)l * 2 * DD2,
            W2t + (size_t)l * 2 * 8192, b2 + (size_t)l * 2 * DD,
            xi_f, xu_f, xhi_o, xhu_o, efi_alt, ef_u, (l == 2) ? 1 : 0, gI);
        __half* tmp = efi; efi = efi_alt; efi_alt = tmp;
    }

    decode_k<<<(NPRED * 16) / 256, 256, 0, stream>>>(xu_f, xi_f, pred, pred + NPRED, out);
}

// Round 11
// 465.615 us; speedup vs baseline: 1.0346x; 1.0346x over previous
//
#include <hip/hip_runtime.h>
#include <hip/hip_fp16.h>

#define NUSR 100000
#define NITM 50000
#define NEDG 1000000
#define NPRED 250000
#define DD 64
#define DD2 128
#define MSG_EPS 1e-7f
#define BN_EPS 1e-5f
#define LOG2E 1.44269504088896340736f
#define LN2F 0.69314718055994530942f

// CSR-build bucketing: items W=512 (shift 9), users W=1024 (shift 10) -> 98 buckets each.
#define KI 98
#define KU 98
#define BCAP 16384  // per-bucket pair capacity (mean 10240, sd ~100 -> 40+ sigma)
#define EPB 4096    // edges per part_k block
#define ICAP 1536   // LDS-staged csr entries per aggemm1 block (overflow -> global path)

typedef _Float16 f16x8 __attribute__((ext_vector_type(8)));
typedef float f32x4 __attribute__((ext_vector_type(4)));

// Journal: R18=475.6us. R19 degree-sort REJECTED (+4us on aggemm1; within-wave
// divergence falsified). Gather ~86us is structural (falsified: arith, bytes@128B,
// ILP, occupancy, cross-wave + within-wave balance) = 2M random 128B row reads.
// R20: exact-R18 aggemm1 restored; final features fp16 (halves decode gather
// traffic + last gemm2 write).

__device__ __forceinline__ float exp2a(float x) {
    float r; asm("v_exp_f32 %0, %1" : "=v"(r) : "v"(x)); return r;
}

// ---- phase 1: partition edges into fixed-capacity bucket pair slots ------------
// Pair packing (27 bits): items (dstoff<<17)|src_user; users (dstoff<<16)|src_item.
__global__ __launch_bounds__(256) void part_k(
    const int* __restrict__ u_idx, const int* __restrict__ i_idx,
    int* __restrict__ bkcnt_i, int* __restrict__ bkcnt_u,
    int* __restrict__ pair_i, int* __restrict__ pair_u)
{
    __shared__ int lh_i[KI], lh_u[KU];
    __shared__ int lb_i[KI], lb_u[KU];
    int tid = threadIdx.x;
    int base = blockIdx.x * EPB;
    int u[16], it[16];
    #pragma unroll
    for (int q = 0; q < 16; q++) {
        int e = base + q * 256 + tid;
        u[q]  = (e < NEDG) ? u_idx[e] : -1;
        it[q] = (e < NEDG) ? i_idx[e] : -1;
    }
    if (tid < KI) lh_i[tid] = 0;
    if (tid >= 128 && tid < 128 + KU) lh_u[tid - 128] = 0;
    __syncthreads();
    #pragma unroll
    for (int q = 0; q < 16; q++) if (it[q] >= 0) {
        atomicAdd(&lh_i[it[q] >> 9], 1);
        atomicAdd(&lh_u[u[q] >> 10], 1);
    }
    __syncthreads();
    if (tid < KI) {
        int c = lh_i[tid];
        lb_i[tid] = tid * BCAP + (c ? atomicAdd(&bkcnt_i[tid], c) : 0);
    }
    if (tid >= 128 && tid < 128 + KU) {
        int k = tid - 128; int c = lh_u[k];
        lb_u[k] = k * BCAP + (c ? atomicAdd(&bkcnt_u[k], c) : 0);
    }
    __syncthreads();
    #pragma unroll
    for (int q = 0; q < 16; q++) if (it[q] >= 0) {
        int pi_ = atomicAdd(&lb_i[it[q] >> 9], 1);
        pair_i[pi_] = ((it[q] & 511) << 17) | u[q];
        int pu_ = atomicAdd(&lb_u[u[q] >> 10], 1);
        pair_u[pu_] = ((u[q] & 1023) << 16) | it[q];
    }
}

// ---- exclusive scan of 98 bucket counts per side (2 blocks x 128) --------------
__global__ __launch_bounds__(128) void bsum2_k(
    const int* __restrict__ bkcnt_i, const int* __restrict__ bkcnt_u,
    int* __restrict__ bbase_i, int* __restrict__ bbase_u)
{
    __shared__ int s[128];
    const int* cnt = (blockIdx.x == 0) ? bkcnt_i : bkcnt_u;
    int* bas = (blockIdx.x == 0) ? bbase_i : bbase_u;
    int t = threadIdx.x;
    int v = (t < KI) ? cnt[t] : 0;
    s[t] = v;
    __syncthreads();
    for (int off = 1; off < 128; off <<= 1) {
        int tv = (t >= off) ? s[t - off] : 0;
        __syncthreads();
        s[t] += tv;
        __syncthreads();
    }
    if (t < KI) bas[t] = s[t] - v;
}

// ---- phase 2: per-bucket block: LDS hist -> LDS scan -> rowptr (coalesced) ->
// LDS-cursor scatter. NO global degree/cursor atomics anywhere. Idempotent.
__global__ __launch_bounds__(1024) void bscat2_k(
    const int* __restrict__ pair_i, const int* __restrict__ pair_u,
    const int* __restrict__ bkcnt_i, const int* __restrict__ bkcnt_u,
    const int* __restrict__ bbase_i, const int* __restrict__ bbase_u,
    int* __restrict__ rowptr_i, int* __restrict__ rowptr_u,
    int* __restrict__ csr_i, int* __restrict__ csr_u)
{
    __shared__ int s[1024];
    __shared__ int cur[1024];
    int b = blockIdx.x;
    const int* pair; int* rowptr; int* csr;
    int base_row, wrows, n, shsrc, cnt, base;
    if (b < KI) {
        pair = pair_i + (size_t)b * BCAP; cnt = bkcnt_i[b]; base = bbase_i[b];
        rowptr = rowptr_i; csr = csr_i; base_row = b << 9; wrows = 512; n = NITM; shsrc = 17;
    } else {
        int k = b - KI;
        pair = pair_u + (size_t)k * BCAP; cnt = bkcnt_u[k]; base = bbase_u[k];
        rowptr = rowptr_u; csr = csr_u; base_row = k << 10; wrows = 1024; n = NUSR; shsrc = 16;
    }
    int nrows = min(wrows, n - base_row);
    int t = threadIdx.x;
    s[t] = 0;
    __syncthreads();
    for (int e = t; e < cnt; e += 1024) atomicAdd(&s[pair[e] >> shsrc], 1);
    __syncthreads();
    int deg = s[t];
    for (int off = 1; off < 1024; off <<= 1) {
        int tv = (t >= off) ? s[t - off] : 0;
        __syncthreads();
        s[t] += tv;
        __syncthreads();
    }
    int rp = base + s[t] - deg;
    if (t < nrows) rowptr[base_row + t] = rp;
    cur[t] = rp;
    if (b == KI - 1 && t == 0) rowptr_i[NITM] = NEDG;
    if (b == KI + KU - 1 && t == 0) rowptr_u[NUSR] = NEDG;
    __syncthreads();
    int srcmask = (1 << shsrc) - 1;
    for (int e = t; e < cnt; e += 1024) {
        int v = pair[e];
        int pos = atomicAdd(&cur[v >> shsrc], 1);
        csr[pos] = v & srcmask;
    }
}

// ========== layer-0 tables: ef = fp16(m*log2e) [128B/row], xh = fp16(x) =========
__global__ __launch_bounds__(256) void msg0_k(
    const float* __restrict__ xu, const float* __restrict__ xi,
    __half* __restrict__ ef_u, __half* __restrict__ ef_i,
    __half* __restrict__ xh_u, __half* __restrict__ xh_i)
{
    int i = blockIdx.x * 256 + threadIdx.x;
    const float* x; __half* ef; __half* xh; int idx;
    if (i < NUSR * 16) { x = xu; ef = ef_u; xh = xh_u; idx = i; }
    else { int j = i - NUSR * 16; if (j >= NITM * 16) return; x = xi; ef = ef_i; xh = xh_i; idx = j; }
    float4 v = ((const float4*)x)[idx];
    float m0 = (fmaxf(v.x, 0.f) + MSG_EPS) * LOG2E;
    float m1 = (fmaxf(v.y, 0.f) + MSG_EPS) * LOG2E;
    float m2 = (fmaxf(v.z, 0.f) + MSG_EPS) * LOG2E;
    float m3 = (fmaxf(v.w, 0.f) + MSG_EPS) * LOG2E;
    __half2 e01 = __floats2half2_rn(m0, m1), e23 = __floats2half2_rn(m2, m3);
    __half2 x01 = __floats2half2_rn(v.x, v.y), x23 = __floats2half2_rn(v.z, v.w);
    uint2 ew, xw;
    ew.x = *(unsigned int*)&e01; ew.y = *(unsigned int*)&e23;
    xw.x = *(unsigned int*)&x01; xw.y = *(unsigned int*)&x23;
    ((uint2*)ef)[idx] = ew;
    ((uint2*)xh)[idx] = xw;
}

// ========== weight convert+transpose to fp16 (once per call) =====================
__global__ __launch_bounds__(256) void wconv_k(
    const float* __restrict__ W1, const float* __restrict__ W2,
    __half* __restrict__ W1t, __half* __restrict__ W2t)
{
    int idx = blockIdx.x * 256 + threadIdx.x;
    if (idx >= 6 * 8192) return;
    int m = idx >> 13, rem = idx & 8191;
    {   // W1 [64][128] -> [128][64]
        int k = rem >> 7, c = rem & 127;
        W1t[m * 8192 + c * 64 + k] = __float2half(W1[idx]);
    }
    {   // W2 [128][64] -> [64][128]
        int k = rem >> 6, c = rem & 63;
        W2t[m * 8192 + c * 128 + k] = __float2half(W2[idx]);
    }
}

// ===== FUSED (item-conv + user-conv) agg + GEMM1 (MFMA fp16) =====================
// den = sum 2^m', num' = sum 2^m' * m', agg = ln2 * num'/den.
// Dynamic row work-queue, unroll-8, rowptr+csr slices in LDS (R18, proven 86.4us).
#define UPD4(U) { \
    float2 va=__half22float2(*(__half2*)&(U).x); \
    float2 vb=__half22float2(*(__half2*)&(U).y); \
    float2 vc=__half22float2(*(__half2*)&(U).z); \
    float2 vd=__half22float2(*(__half2*)&(U).w); \
    float e0=exp2a(va.x), e1=exp2a(va.y), e2=exp2a(vb.x), e3=exp2a(vb.y); \
    float e4=exp2a(vc.x), e5=exp2a(vc.y), e6=exp2a(vd.x), e7=exp2a(vd.y); \
    d0+=e0; n0=fmaf(e0,va.x,n0); d1+=e1; n1=fmaf(e1,va.y,n1); \
    d2+=e2; n2=fmaf(e2,vb.x,n2); d3+=e3; n3=fmaf(e3,vb.y,n3); \
    d4+=e4; n4=fmaf(e4,vc.x,n4); d5+=e5; n5=fmaf(e5,vc.y,n5); \
    d6+=e6; n6=fmaf(e6,vd.x,n6); d7+=e7; n7=fmaf(e7,vd.y,n7); }

#define GBODY(IDXE) { \
    int j = beg; \
    for (; j + 8 <= end; j += 8) { \
        int s0=(IDXE(j)),   s1=(IDXE(j+1)), s2=(IDXE(j+2)), s3=(IDXE(j+3)); \
        int s4=(IDXE(j+4)), s5=(IDXE(j+5)), s6=(IDXE(j+6)), s7=(IDXE(j+7)); \
        uint4 u0 = mp4[(size_t)s0*8+l8]; uint4 u1 = mp4[(size_t)s1*8+l8]; \
        uint4 u2 = mp4[(size_t)s2*8+l8]; uint4 u3 = mp4[(size_t)s3*8+l8]; \
        uint4 u4 = mp4[(size_t)s4*8+l8]; uint4 u5 = mp4[(size_t)s5*8+l8]; \
        uint4 u6 = mp4[(size_t)s6*8+l8]; uint4 u7 = mp4[(size_t)s7*8+l8]; \
        UPD4(u0) UPD4(u1) UPD4(u2) UPD4(u3) UPD4(u4) UPD4(u5) UPD4(u6) UPD4(u7) } \
    for (; j + 2 <= end; j += 2) { \
        int s0=(IDXE(j)), s1=(IDXE(j+1)); \
        uint4 u0 = mp4[(size_t)s0*8+l8]; uint4 u1 = mp4[(size_t)s1*8+l8]; \
        UPD4(u0) UPD4(u1) } \
    if (j < end) { int ss=(IDXE(j)); uint4 uu = mp4[(size_t)ss*8+l8]; UPD4(uu) } }

#define IDX_L(jj) su.idx[(jj)]
#define IDX_G(jj) csr[blkBeg + (jj)]

union AggSU { int idx[ICAP]; float red[8][128]; };

__global__ __launch_bounds__(256) void aggemm1f_k(
    const __half* __restrict__ ef_i_src, const __half* __restrict__ ef_u_src,
    const __half* __restrict__ xhi_cur, const __half* __restrict__ xhu_cur,
    const int* __restrict__ rowptr_i, const int* __restrict__ rowptr_u,
    const int* __restrict__ csr_i, const int* __restrict__ csr_u,
    const __half* __restrict__ W1t_l,   // layer base: [2][128][64] f16
    const float* __restrict__ b1_l,     // [2][128]
    __half* __restrict__ h1_i, __half* __restrict__ h1_u,   // fp16 h1
    double* __restrict__ gs_l,          // [2][256] (gsum|gsq per conv)
    int gI)
{
    __shared__ _Float16 sA[64][88];      // 11.3 KB, rows 16B-aligned
    __shared__ AggSU su;                 // 6 KB (idx) / 4 KB (red)
    __shared__ int srp[65];              // rowptr slice (relative to blkBeg)
    __shared__ int wq;                   // dynamic row queue

    int side = ((int)blockIdx.x < gI) ? 0 : 1;
    int bb = side ? (blockIdx.x - gI) : blockIdx.x;
    const __half* ef  = side ? ef_i_src : ef_u_src;   // side0 (item dst) gathers USER msgs
    const __half* xh  = side ? xhu_cur : xhi_cur;     // dst features
    const int* rowptr = side ? rowptr_u : rowptr_i;
    const int* csr    = side ? csr_u : csr_i;
    const __half* W1t = W1t_l + (size_t)side * 8192;
    const float* b1   = b1_l + side * DD2;
    __half* h1        = side ? h1_u : h1_i;
    double* gsum      = gs_l + side * 256;
    double* gsq       = gsum + 128;
    int N             = side ? NUSR : NITM;

    int t = threadIdx.x;
    int r0 = bb * 64;
    int w = t >> 6, lane = t & 63;
    int g = lane >> 3, l8 = lane & 7;          // gather layout: 8 lanes/row
    int q = lane >> 4, ln = lane & 15;         // MFMA layout
    const uint4* mp4 = (const uint4*)ef;

    // ---- stage csr slice + rowptr slice (coalesced, off the dependent chain) --
    int blkBeg = rowptr[r0];
    if (t == 0) wq = 0;
    if (t < 65) srp[t] = rowptr[min(r0 + t, N)] - blkBeg;
    int blkEnd = rowptr[min(r0 + 64, N)];
    int nE = blkEnd - blkBeg;
    for (int e = t; e < nE && e < ICAP; e += 256) su.idx[e] = csr[blkBeg + e];
    __syncthreads();

    // ---- gather + softmax-agg: 32 groups pull rows dynamically ----------------
    for (;;) {
        int rr = 0;
        if (l8 == 0) rr = atomicAdd(&wq, 1);
        rr = __shfl(rr, g * 8);
        if (rr >= 64) break;
        int r = r0 + rr;
        uint4 o = make_uint4(0u, 0u, 0u, 0u);
        if (r < N) {
            uint4 xv = ((const uint4*)xh)[(size_t)r * 8 + l8];   // early, independent
            int beg = srp[rr], end = srp[rr + 1];
            float d0=0.f,d1=0.f,d2=0.f,d3=0.f,d4=0.f,d5=0.f,d6=0.f,d7=0.f;
            float n0=0.f,n1=0.f,n2=0.f,n3=0.f,n4=0.f,n5=0.f,n6=0.f,n7=0.f;
            if (end <= ICAP) { GBODY(IDX_L) } else { GBODY(IDX_G) }
            bool nz = end > beg;
            float a0 = nz ? (n0/d0)*LN2F : 0.f, a1 = nz ? (n1/d1)*LN2F : 0.f;
            float a2 = nz ? (n2/d2)*LN2F : 0.f, a3 = nz ? (n3/d3)*LN2F : 0.f;
            float a4 = nz ? (n4/d4)*LN2F : 0.f, a5 = nz ? (n5/d5)*LN2F : 0.f;
            float a6 = nz ? (n6/d6)*LN2F : 0.f, a7 = nz ? (n7/d7)*LN2F : 0.f;
            float2 x01 = __half22float2(*(__half2*)&xv.x);
            float2 x23 = __half22float2(*(__half2*)&xv.y);
            float2 x45 = __half22float2(*(__half2*)&xv.z);
            float2 x67 = __half22float2(*(__half2*)&xv.w);
            __half2 p0 = __floats2half2_rn(a0 + x01.x, a1 + x01.y);
            __half2 p1 = __floats2half2_rn(a2 + x23.x, a3 + x23.y);
            __half2 p2 = __floats2half2_rn(a4 + x45.x, a5 + x45.y);
            __half2 p3 = __floats2half2_rn(a6 + x67.x, a7 + x67.y);
            o.x = *(unsigned int*)&p0; o.y = *(unsigned int*)&p1;
            o.z = *(unsigned int*)&p2; o.w = *(unsigned int*)&p3;
        }
        *(uint4*)&sA[rr][l8 * 8] = o;
    }
    __syncthreads();

    f16x8 afr[4][2], bfr[2][2];
    #pragma unroll
    for (int rt = 0; rt < 4; rt++)
        #pragma unroll
        for (int ks = 0; ks < 2; ks++)
            afr[rt][ks] = *(const f16x8*)&sA[rt * 16 + ln][ks * 32 + q * 8];
    const f16x8* Wv = (const f16x8*)W1t;   // [row 0..127][k-frag]: idx = row*8 + ks*4 + q
    #pragma unroll
    for (int ct = 0; ct < 2; ct++)
        #pragma unroll
        for (int ks = 0; ks < 2; ks++)
            bfr[ct][ks] = Wv[(w * 32 + ct * 16 + ln) * 8 + ks * 4 + q];

    f32x4 acc[4][2];
    #pragma unroll
    for (int rt = 0; rt < 4; rt++)
        #pragma unroll
        for (int ct = 0; ct < 2; ct++)
            acc[rt][ct] = (f32x4){0.f, 0.f, 0.f, 0.f};

    #pragma unroll
    for (int rt = 0; rt < 4; rt++)
        #pragma unroll
        for (int ct = 0; ct < 2; ct++) {
            acc[rt][ct] = __builtin_amdgcn_mfma_f32_16x16x32_f16(
                afr[rt][0], bfr[ct][0], acc[rt][ct], 0, 0, 0);
            acc[rt][ct] = __builtin_amdgcn_mfma_f32_16x16x32_f16(
                afr[rt][1], bfr[ct][1], acc[rt][ct], 0, 0, 0);
        }

    float b1c0 = b1[w * 32 + ln];
    float b1c1 = b1[w * 32 + 16 + ln];
    float ps0 = 0.f, pq0 = 0.f, ps1 = 0.f, pq1 = 0.f;
    #pragma unroll
    for (int rt = 0; rt < 4; rt++) {
        #pragma unroll
        for (int i = 0; i < 4; i++) {
            int r = r0 + rt * 16 + q * 4 + i;
            if (r < N) {
                float h0 = acc[rt][0][i] + b1c0;
                float h1v = acc[rt][1][i] + b1c1;
                h1[(size_t)r * DD2 + w * 32 + ln] = __float2half(h0);
                h1[(size_t)r * DD2 + w * 32 + 16 + ln] = __float2half(h1v);
                ps0 += h0; pq0 += h0 * h0;
                ps1 += h1v; pq1 += h1v * h1v;
            }
        }
    }
    // su.idx is dead (last read before the pre-MFMA barrier) -> reuse as red scratch
    su.red[q][w * 32 + ln] = ps0;      su.red[q][w * 32 + 16 + ln] = ps1;
    su.red[4 + q][w * 32 + ln] = pq0;  su.red[4 + q][w * 32 + 16 + ln] = pq1;
    __syncthreads();
    if (t < 128) {
        float s = 0.f, qq = 0.f;
        #pragma unroll
        for (int k = 0; k < 4; k++) { s += su.red[k][t]; qq += su.red[4 + k][t]; }
        atomicAdd(&gsum[t], (double)s);
        atomicAdd(&gsq[t],  (double)qq);
    }
}

// ===== FUSED GEMM2 (both convs): xnew = relu(relu(bn(h1)) @ W2 + b2) ============
// last=0: write fp16 xh + fp16 ef (m*log2e). last=1: write fp16 xh only (decode
// reads fp16 — R20).
__global__ __launch_bounds__(256) void gemm2f_k(
    const __half* __restrict__ h1_i, const __half* __restrict__ h1_u,
    const double* __restrict__ gs_l,
    const float* __restrict__ gamma_l, const float* __restrict__ beta_l,
    const __half* __restrict__ W2t_l, const float* __restrict__ b2_l,
    __half* __restrict__ xhi_out, __half* __restrict__ xhu_out,
    __half* __restrict__ efi_out, __half* __restrict__ efu_out,
    int last, int gI)
{
    __shared__ _Float16 sA[64][136];    // 17.4 KB
    __shared__ float2 sss[DD2];         // 1 KB

    int side = ((int)blockIdx.x < gI) ? 0 : 1;
    int bb = side ? (blockIdx.x - gI) : blockIdx.x;
    const __half* h1   = side ? h1_u : h1_i;
    const double* gsum = gs_l + side * 256;
    const double* gsq  = gsum + 128;
    const float* gamma = gamma_l + side * DD2;
    const float* beta  = beta_l + side * DD2;
    const __half* W2t  = W2t_l + (size_t)side * 8192;
    const float* b2    = b2_l + side * DD;
    __half* xhout      = side ? xhu_out : xhi_out;
    __half* efout      = side ? efu_out : efi_out;
    int N              = side ? NUSR : NITM;

    int t = threadIdx.x;
    if (t < 128) {
        double mean = gsum[t] / (double)N;
        double var  = gsq[t] / (double)N - mean * mean;
        float inv = (float)(1.0 / sqrt(var + (double)BN_EPS));
        float sc = gamma[t] * inv;
        sss[t] = make_float2(sc, beta[t] - (float)mean * sc);
    }
    __syncthreads();

    int r0 = bb * 64;
    // stage h1 (fp16) with BN + relu -> fp16: 64 rows x 32 uint2 (4 halves each)
    for (int i = t; i < 2048; i += 256) {
        int rr = i >> 5, c4 = i & 31;
        int r = r0 + rr;
        uint2 o = make_uint2(0u, 0u);
        if (r < N) {
            uint2 hv = ((const uint2*)h1)[(size_t)r * 32 + c4];
            float2 va = __half22float2(*(__half2*)&hv.x);
            float2 vb = __half22float2(*(__half2*)&hv.y);
            float2 s0 = sss[c4 * 4], s1 = sss[c4 * 4 + 1];
            float2 s2 = sss[c4 * 4 + 2], s3 = sss[c4 * 4 + 3];
            va.x = fmaxf(fmaf(va.x, s0.x, s0.y), 0.f);
            va.y = fmaxf(fmaf(va.y, s1.x, s1.y), 0.f);
            vb.x = fmaxf(fmaf(vb.x, s2.x, s2.y), 0.f);
            vb.y = fmaxf(fmaf(vb.y, s3.x, s3.y), 0.f);
            __half2 a = __floats2half2_rn(va.x, va.y);
            __half2 b = __floats2half2_rn(vb.x, vb.y);
            o.x = *(unsigned int*)&a; o.y = *(unsigned int*)&b;
        }
        *(uint2*)&sA[rr][c4 * 4] = o;
    }
    __syncthreads();

    int w = t >> 6, lane = t & 63, q = lane >> 4, ln = lane & 15;
    f32x4 acc[4];
    #pragma unroll
    for (int rt = 0; rt < 4; rt++) acc[rt] = (f32x4){0.f, 0.f, 0.f, 0.f};

    const f16x8* Wv = (const f16x8*)W2t;   // [row 0..63][k-frag]: idx = row*16 + ks*4 + q
    #pragma unroll
    for (int ks = 0; ks < 4; ks++) {
        f16x8 bf = Wv[(w * 16 + ln) * 16 + ks * 4 + q];
        #pragma unroll
        for (int rt = 0; rt < 4; rt++) {
            f16x8 af = *(const f16x8*)&sA[rt * 16 + ln][ks * 32 + q * 8];
            acc[rt] = __builtin_amdgcn_mfma_f32_16x16x32_f16(af, bf, acc[rt], 0, 0, 0);
        }
    }

    int c = w * 16 + ln;
    float bb2 = b2[c];
    #pragma unroll
    for (int rt = 0; rt < 4; rt++) {
        #pragma unroll
        for (int i = 0; i < 4; i++) {
            int r = r0 + rt * 16 + q * 4 + i;
            if (r < N) {
                float o = fmaxf(acc[rt][i] + bb2, 0.f);
                xhout[(size_t)r * DD + c] = __float2half(o);
                if (!last)
                    efout[(size_t)r * DD + c] = __float2half((o + MSG_EPS) * LOG2E);
            }
        }
    }
}

// ================= decoder (fp16 features, 8 lanes/pair) =========================
__global__ __launch_bounds__(256) void decode_k(
    const __half* __restrict__ xu, const __half* __restrict__ xi,
    const int* __restrict__ pu, const int* __restrict__ pi,
    float* __restrict__ out)
{
    int idx = blockIdx.x * 256 + threadIdx.x;
    int b = idx >> 3, lane = idx & 7;
    if (b >= NPRED) return;
    int u = pu[b], it = pi[b];
    uint4 a = ((const uint4*)(xu + (size_t)u * DD))[lane];
    uint4 c = ((const uint4*)(xi + (size_t)it * DD))[lane];
    float s = 0.f;
    const __half2* ah = (const __half2*)&a;
    const __half2* ch = (const __half2*)&c;
    #pragma unroll
    for (int k = 0; k < 4; k++) {
        float2 fa = __half22float2(ah[k]);
        float2 fc = __half22float2(ch[k]);
        s = fmaf(fa.x, fc.x, s);
        s = fmaf(fa.y, fc.y, s);
    }
    #pragma unroll
    for (int off = 4; off; off >>= 1) s += __shfl_down(s, off, 8);
    if (lane == 0) out[b] = s;
}

extern "C" void kernel_launch(void* const* d_in, const int* in_sizes, int n_in,
                              void* d_out, int out_size, void* d_ws, size_t ws_size,
                              hipStream_t stream)
{
    const float* x_user = (const float*)d_in[0];
    const float* x_item = (const float*)d_in[1];
    const float* W1    = (const float*)d_in[2];   // [3][2][64][128]
    const float* b1    = (const float*)d_in[3];
    const float* gamma = (const float*)d_in[4];
    const float* beta  = (const float*)d_in[5];
    const float* W2    = (const float*)d_in[6];   // [3][2][128][64]
    const float* b2    = (const float*)d_in[7];
    const int* edge = (const int*)d_in[8];        // [2][E]
    const int* pred = (const int*)d_in[9];        // [2][B]
    float* out = (float*)d_out;

    const int* u_idx = edge;
    const int* i_idx = edge + NEDG;

    // ---- workspace bump allocator (256B aligned chunks) ----
    char* p = (char*)d_ws;
    #define ALLOC(ptr, type, count) \
        type* ptr = (type*)p; p += (((size_t)(count) * sizeof(type)) + 255) & ~(size_t)255;

    ALLOC(gsumAll, double, 12 * 256)             // 6 convs x (gsum[128]|gsq[128])
    ALLOC(bkcnt_i, int, 128)
    ALLOC(bkcnt_u, int, 128)
    size_t zero_span = (char*)p - (char*)gsumAll;
    ALLOC(bbase_i, int, 128)
    ALLOC(bbase_u, int, 128)
    ALLOC(rowptr_i, int, NITM + 1)
    ALLOC(rowptr_u, int, NUSR + 1)
    ALLOC(csr_i, int, NEDG)
    ALLOC(csr_u, int, NEDG)
    ALLOC(h1_i, __half, (size_t)NITM * DD2)
    ALLOC(h1_u, __half, (size_t)NUSR * DD2)
    ALLOC(W1t, __half, 6 * 8192)
    ALLOC(W2t, __half, 6 * 8192)
    ALLOC(xh_u0, __half, (size_t)NUSR * DD)
    ALLOC(xh_u1, __half, (size_t)NUSR * DD)
    ALLOC(xh_i0, __half, (size_t)NITM * DD)
    ALLOC(xh_i1, __half, (size_t)NITM * DD)
    ALLOC(ef_u, __half, (size_t)NUSR * DD)
    ALLOC(ef_i0, __half, (size_t)NITM * DD)
    ALLOC(ef_i1, __half, (size_t)NITM * DD)
    #undef ALLOC

    // fixed-capacity bucket pair slots alias h1 buffers: pairs are consumed by
    // bscat2_k strictly BEFORE aggemm1f_k first writes h1 (same stream).
    // pair_i 6.4MB <= h1_i 12.8MB; pair_u 6.4MB <= h1_u 25.6MB.
    int* pair_i = (int*)h1_i;
    int* pair_u = (int*)h1_u;

    // ---- CSR build + converts (once; reused by all 3 layers) ----
    hipMemsetAsync(gsumAll, 0, zero_span, stream);
    int pb = (NEDG + EPB - 1) / EPB;          // 245
    part_k<<<pb, 256, 0, stream>>>(u_idx, i_idx, bkcnt_i, bkcnt_u, pair_i, pair_u);
    bsum2_k<<<2, 128, 0, stream>>>(bkcnt_i, bkcnt_u, bbase_i, bbase_u);
    bscat2_k<<<KI + KU, 1024, 0, stream>>>(pair_i, pair_u, bkcnt_i, bkcnt_u,
                                           bbase_i, bbase_u, rowptr_i, rowptr_u,
                                           csr_i, csr_u);

    wconv_k<<<(6 * 8192 + 255) / 256, 256, 0, stream>>>(W1, W2, W1t, W2t);
    msg0_k<<<((NUSR + NITM) * 16 + 255) / 256, 256, 0, stream>>>(
        x_user, x_item, ef_u, ef_i0, xh_u0, xh_i0);

    // ---- 3 layers, each = 1 fused aggemm1 + 1 fused gemm2 ----
    int gI = (NITM + 63) / 64;    // 782 item blocks
    int gU = (NUSR + 63) / 64;    // 1563 user blocks
    __half* efi = ef_i0;
    __half* efi_alt = ef_i1;
    for (int l = 0; l < 3; l++) {
        const __half* xhi_c = (l & 1) ? xh_i1 : xh_i0;
        const __half* xhu_c = (l & 1) ? xh_u1 : xh_u0;
        __half* xhi_o = (l & 1) ? xh_i0 : xh_i1;
        __half* xhu_o = (l & 1) ? xh_u0 : xh_u1;
        aggemm1f_k<<<gI + gU, 256, 0, stream>>>(
            efi, ef_u, xhi_c, xhu_c, rowptr_i, rowptr_u, csr_i, csr_u,
            W1t + (size_t)l * 2 * 8192, b1 + (size_t)l * 2 * DD2,
            h1_i, h1_u, gsumAll + l * 2 * 256, gI);
        gemm2f_k<<<gI + gU, 256, 0, stream>>>(
            h1_i, h1_u, gsumAll + l * 2 * 256,
            gamma + (size_t)l * 2 * DD2, beta + (size_t)l * 2 * DD2,
            W2t + (size_t)l * 2 * 8192, b2 + (size_t)l * 2 * DD,
            xhi_o, xhu_o, efi_alt, ef_u, (l == 2) ? 1 : 0, gI);
        __half* tmp = efi; efi = efi_alt; efi_alt = tmp;
    }

    // final features live in xh_u1 / xh_i1 (l=2 writes the "1" buffers)
    decode_k<<<(NPRED * 8 + 255) / 256, 256, 0, stream>>>(
        xh_u1, xh_i1, pred, pred + NPRED, out);
}